// Round 20
// baseline (257.259 us; speedup 1.0000x reference)
//
#include <hip/hip_runtime.h>
#include <math.h>

#define B_ 4
#define T_ 2048
#define C_ 1024
#define NH_ 16
#define NKV_ 8
#define HD_ 64
#define KACT_ 8
#define VG_ 32
#define EPS_ 1e-6f
#define LOG2E_ 1.44269504088896340736f

typedef __attribute__((ext_vector_type(8))) short bf16x8;
typedef __attribute__((ext_vector_type(4))) float f32x4;
typedef __attribute__((ext_vector_type(4))) unsigned short u16x4;
typedef unsigned short u16;
typedef unsigned int u32;

__device__ inline u16 f2bf(float f) {
    u32 u = __float_as_uint(f);
    u += 0x7fffu + ((u >> 16) & 1u);   // RNE (finite data)
    return (u16)(u >> 16);
}

__device__ inline u16 f2bf_t(float f) {        // truncating (P>=0 softmax weights only)
    return (u16)(__float_as_uint(f) >> 16);
}

__device__ inline float fast_exp2(float x) {   // bare v_exp_f32 (D = 2^S0), no libm guards
    float r;
    asm("v_exp_f32 %0, %1" : "=v"(r) : "v"(x));
    return r;
}

__device__ inline void gload_lds16(const void* g, void* s) {
    __builtin_amdgcn_global_load_lds((const __attribute__((address_space(1))) void*)g,
                                     (__attribute__((address_space(3))) void*)s, 16, 0, 0);
}

__device__ inline void bar() {                 // raw barrier + compiler memory fence
    asm volatile("" ::: "memory");
    __builtin_amdgcn_s_barrier();
    asm volatile("" ::: "memory");
}

// st_16x32 swizzle (involution): byte ^= ((byte>>9)&1)<<5
__device__ inline int swz(int b) { return b ^ (((b >> 9) & 1) << 5); }

// ===================== fused weight casts: Wq|Wk|Wv -> wqkv, Wo -> wo =====================
__global__ __launch_bounds__(256) void cast_weights_kernel(
    const float* __restrict__ Wq, const float* __restrict__ Wk,
    const float* __restrict__ Wv, const float* __restrict__ Wo,
    u16* __restrict__ wqkv, u16* __restrict__ wo)
{
    int i = blockIdx.x * 256 + threadIdx.x;    // 786432 float4 chunks total
    const float* src; u16* dst; int j;
    if (i < 262144)      { src = Wq; dst = wqkv;           j = i; }
    else if (i < 393216) { src = Wk; dst = wqkv + 1048576; j = i - 262144; }
    else if (i < 524288) { src = Wv; dst = wqkv + 1572864; j = i - 393216; }
    else                 { src = Wo; dst = wo;             j = i - 524288; }
    float4 v = ((const float4*)src)[j];
    u16x4 o = { f2bf(v.x), f2bf(v.y), f2bf(v.z), f2bf(v.w) };
    ((u16x4*)dst)[j] = o;
}

// ===================== QKV GEMM: 256x256 tile, wave tile 128x64 (64 MFMA : 24 reads) ====
// A: xb (Mx1024), W: wqkv (2048x1024). 512 threads = 8 waves (2M x 4N). BK=64.
// A,B double-buffered (64KB+64KB = 128KB LDS, 1 block/CU, grid 8x32 = 256 = 1/CU).
// 2-barrier loop; stage kt+1 targets the non-read buffer (race-free). kt/kk order
// identical to prior kernels -> bit-identical outputs. st_16x32 swizzle involution.
// Epilogue: q f32 / k f32 / v bf16+gate*ve written transposed as vbT[b][kv][d][t].
__global__ __launch_bounds__(512) void gemm_qkv_256x256(
    const u16* __restrict__ A, const u16* __restrict__ W, int M, int K,
    float* __restrict__ q_out, float* __restrict__ k_out, u16* __restrict__ vT_out,
    const float* __restrict__ gate, const float* __restrict__ ve)
{
    __shared__ __align__(16) u16 AL[2][256 * 64];      // 64 KB
    __shared__ __align__(16) u16 BL[2][256 * 64];      // 64 KB
    const int tid = threadIdx.x;
    const int lane = tid & 63;
    const int w = tid >> 6;
    const int bm = blockIdx.y * 256;
    const int bn = blockIdx.x * 256;
    const int wm = (w >> 2) * 128;
    const int wn = (w & 3) * 64;
    const int lr = lane & 15, lg = lane >> 4;
    const int NKT = K >> 6;            // 16

    f32x4 acc[8][4];
    #pragma unroll
    for (int mi = 0; mi < 8; ++mi)
        #pragma unroll
        for (int ni = 0; ni < 4; ++ni) acc[mi][ni] = f32x4{0.f, 0.f, 0.f, 0.f};

    auto stageA = [&](int kt) {        // 4 chunks/thread (2048 chunks of 16B)
        const int db = kt & 1;
        #pragma unroll
        for (int ci = 0; ci < 4; ++ci) {
            int c = tid + ci * 512;
            int l = c ^ (((c >> 5) & 1) << 1);
            gload_lds16(A + (size_t)(bm + (l >> 3)) * K + kt * 64 + (l & 7) * 8,
                        (char*)&AL[db][0] + c * 16);
        }
    };
    auto stageB = [&](int kt) {
        const int db = kt & 1;
        #pragma unroll
        for (int ci = 0; ci < 4; ++ci) {
            int c = tid + ci * 512;
            int l = c ^ (((c >> 5) & 1) << 1);
            gload_lds16(W + (size_t)(bn + (l >> 3)) * K + kt * 64 + (l & 7) * 8,
                        (char*)&BL[db][0] + c * 16);
        }
    };

    stageA(0);
    stageB(0);
    for (int kt = 0; kt < NKT; ++kt) {
        const int db = kt & 1;
        asm volatile("s_waitcnt vmcnt(0)" ::: "memory");
        bar();                          // buf[db] for K-tile kt landed block-wide
        bf16x8 af[8][2], bfm[4][2];
        #pragma unroll
        for (int mi = 0; mi < 8; ++mi) {
            const int row = wm + mi * 16 + lr;
            #pragma unroll
            for (int kk = 0; kk < 2; ++kk)
                af[mi][kk] = *(const bf16x8*)((const char*)&AL[db][0] +
                                              swz(row * 128 + kk * 64 + lg * 16));
        }
        #pragma unroll
        for (int ni = 0; ni < 4; ++ni) {
            const int row = wn + ni * 16 + lr;
            #pragma unroll
            for (int kk = 0; kk < 2; ++kk)
                bfm[ni][kk] = *(const bf16x8*)((const char*)&BL[db][0] +
                                               swz(row * 128 + kk * 64 + lg * 16));
        }
        if (kt + 1 < NKT) { stageA(kt + 1); stageB(kt + 1); }   // -> buf[db^1]
        __builtin_amdgcn_s_setprio(1);
        #pragma unroll
        for (int mi = 0; mi < 8; ++mi)
            #pragma unroll
            for (int ni = 0; ni < 4; ++ni)
                #pragma unroll
                for (int kk = 0; kk < 2; ++kk)
                    acc[mi][ni] = __builtin_amdgcn_mfma_f32_16x16x32_bf16(
                        af[mi][kk], bfm[ni][kk], acc[mi][ni], 0, 0, 0);
        __builtin_amdgcn_s_setprio(0);
        bar();                          // all waves done reading buf[db]
    }

    #pragma unroll
    for (int mi = 0; mi < 8; ++mi)
        #pragma unroll
        for (int ni = 0; ni < 4; ++ni) {
            const int row0 = bm + wm + mi * 16 + lg * 4;   // 4 consecutive tokens, same b
            const int col = bn + wn + ni * 16 + lr;
            if (col < 1024) {
                #pragma unroll
                for (int r = 0; r < 4; ++r)
                    q_out[(size_t)(row0 + r) * 1024 + col] = acc[mi][ni][r];
            } else if (col < 1536) {
                #pragma unroll
                for (int r = 0; r < 4; ++r)
                    k_out[(size_t)(row0 + r) * 512 + (col - 1024)] = acc[mi][ni][r];
            } else {
                const int cc = col - 1536;
                const int kv = cc >> 6, d = cc & 63;
                u16x4 pk;
                #pragma unroll
                for (int r = 0; r < 4; ++r) {
                    const int row = row0 + r;
                    pk[r] = f2bf(acc[mi][ni][r] +
                                 gate[row * NKV_ + kv] * ve[(size_t)row * 512 + cc]);
                }
                *(u16x4*)(vT_out + ((size_t)((row0 >> 11) * NKV_ + kv) * HD_ + d) * T_ +
                          (row0 & (T_ - 1))) = pk;
            }
        }
}

// ===================== bf16 NT-GEMM: 256x128 tile, counted-vmcnt pipeline (R16-proven) ==
// Used for Wo. A triple-buffered, B double-buffered; vmcnt(4) at K-tile entry.
template<int MODE>
__global__ __launch_bounds__(512) void gemm_bf16_256(
    const u16* __restrict__ A, const u16* __restrict__ W,
    float* __restrict__ Out, int M, int N, int K)
{
    __shared__ __align__(16) u16 AL[3][2][128 * 64];   // 96 KB
    __shared__ __align__(16) u16 BL[2][128 * 64];      // 32 KB
    const int tid = threadIdx.x;
    const int lane = tid & 63;
    const int w = tid >> 6;
    const int bm = blockIdx.y * 256;
    const int bn = blockIdx.x * 128;
    const int wm = (w >> 2) * 128;     // A half = w>>2
    const int wn = (w & 3) * 32;
    const int ah = w >> 2;
    const int lr = lane & 15, lg = lane >> 4;
    const int NKT = K >> 6;            // 16

    f32x4 acc[8][2];
    #pragma unroll
    for (int mi = 0; mi < 8; ++mi)
        #pragma unroll
        for (int ni = 0; ni < 2; ++ni) acc[mi][ni] = f32x4{0.f, 0.f, 0.f, 0.f};

    auto stageA = [&](int kt) {        // both halves, 4 loads FIFO
        const int db = kt % 3;
        #pragma unroll
        for (int hf = 0; hf < 2; ++hf)
            #pragma unroll
            for (int ci = 0; ci < 2; ++ci) {
                int c = tid + ci * 512;
                int l = c ^ (((c >> 5) & 1) << 1);
                gload_lds16(A + (size_t)(bm + hf * 128 + (l >> 3)) * K + kt * 64 + (l & 7) * 8,
                            (char*)&AL[db][hf][0] + c * 16);
            }
    };
    auto stageB = [&](int kt) {        // 2 loads
        const int db = kt & 1;
        #pragma unroll
        for (int ci = 0; ci < 2; ++ci) {
            int c = tid + ci * 512;
            int l = c ^ (((c >> 5) & 1) << 1);
            gload_lds16(W + (size_t)(bn + (l >> 3)) * K + kt * 64 + (l & 7) * 8,
                        (char*)&BL[db][0] + c * 16);
        }
    };

    stageA(0);
    stageB(0);
    stageA(1);                          // FIFO: [A0(4), B0(2), A1(4)]

    for (int kt = 0; kt < NKT; ++kt) {
        const int ab = kt % 3, bb = kt & 1;
        if (kt == NKT - 1) asm volatile("s_waitcnt vmcnt(0)" ::: "memory");
        else               asm volatile("s_waitcnt vmcnt(4)" ::: "memory");
        bar();                          // all waves' loads for K-tile kt landed
        #pragma unroll
        for (int ph = 0; ph < 2; ++ph) {
            bf16x8 af[4][2], bfm[2][2];
            #pragma unroll
            for (int mi2 = 0; mi2 < 4; ++mi2) {
                const int row = (ph * 4 + mi2) * 16 + lr;
                #pragma unroll
                for (int kk = 0; kk < 2; ++kk)
                    af[mi2][kk] = *(const bf16x8*)((const char*)&AL[ab][ah][0] +
                                                   swz(row * 128 + kk * 64 + lg * 16));
            }
            #pragma unroll
            for (int ni = 0; ni < 2; ++ni) {
                const int row = wn + ni * 16 + lr;
                #pragma unroll
                for (int kk = 0; kk < 2; ++kk)
                    bfm[ni][kk] = *(const bf16x8*)((const char*)&BL[bb][0] +
                                                   swz(row * 128 + kk * 64 + lg * 16));
            }
            if (ph == 0) { if (kt + 1 < NKT) stageB(kt + 1); }
            else         { if (kt + 2 < NKT) stageA(kt + 2); }
            bar();
            __builtin_amdgcn_s_setprio(1);
            #pragma unroll
            for (int mi2 = 0; mi2 < 4; ++mi2)
                #pragma unroll
                for (int ni = 0; ni < 2; ++ni)
                    #pragma unroll
                    for (int kk = 0; kk < 2; ++kk)
                        acc[ph * 4 + mi2][ni] = __builtin_amdgcn_mfma_f32_16x16x32_bf16(
                            af[mi2][kk], bfm[ni][kk], acc[ph * 4 + mi2][ni], 0, 0, 0);
            __builtin_amdgcn_s_setprio(0);
            bar();
        }
    }

    #pragma unroll
    for (int mi = 0; mi < 8; ++mi)
        #pragma unroll
        for (int ni = 0; ni < 2; ++ni) {
            const int row0 = bm + wm + mi * 16 + lg * 4;
            const int col = bn + wn + ni * 16 + lr;
            #pragma unroll
            for (int r = 0; r < 4; ++r)
                Out[(size_t)(row0 + r) * N + col] = acc[mi][ni][r];
        }
}

// ===================== Router + top-8 mask + gate + fused x->bf16 cast (R12-proven) ====
__global__ __launch_bounds__(64) void logits_mask_gate_kernel(
    const float* __restrict__ x, const float* __restrict__ Wr,
    const float* __restrict__ Wg, float* __restrict__ hm, float* __restrict__ gate,
    u16* __restrict__ xb)
{
    const int token = blockIdx.x;
    const int lane = threadIdx.x;
    const float* xr = x + (size_t)token * C_;
    __shared__ float lg[NH_];
    __shared__ float thr_s;
    float part[NH_];
    #pragma unroll
    for (int h = 0; h < NH_; ++h) part[h] = 0.f;
    for (int c = lane; c < C_; c += 64) {
        float xv = xr[c];
        xb[(size_t)token * C_ + c] = f2bf(xv);   // fused cast
        #pragma unroll
        for (int h = 0; h < NH_; ++h) part[h] = fmaf(xv, Wr[h * C_ + c], part[h]);
    }
    #pragma unroll
    for (int h = 0; h < NH_; ++h) {
        float s = part[h];
        #pragma unroll
        for (int off = 32; off; off >>= 1) s += __shfl_xor(s, off);
        if (lane == 0) lg[h] = s;
    }
    __syncthreads();
    if (lane == 0) {
        unsigned used = 0;
        float last = 0.f;
        for (int p = 0; p < KACT_; ++p) {
            float bv = -3.4e38f; int bi = 0;
            for (int i = 0; i < NH_; ++i)
                if (!(used & (1u << i)) && lg[i] > bv) { bv = lg[i]; bi = i; }
            used |= 1u << bi;
            last = bv;
        }
        thr_s = last;
    }
    __syncthreads();
    if (lane < NH_) hm[(size_t)token * NH_ + lane] = (lg[lane] >= thr_s) ? 1.f : 0.f;
    if (lane < NKV_) {
        float s = 0.f;
        #pragma unroll
        for (int g = 0; g < VG_; ++g) s = fmaf(xr[g], Wg[lane * VG_ + g], s);
        gate[(size_t)token * NKV_ + lane] = 2.f / (1.f + __expf(-s));
    }
}

// ===================== rotary + rms-norm, 16-vec/block, HEAD-major out (R7-proven) ====
__global__ __launch_bounds__(256) void rope_rms_kernel(
    const float* __restrict__ src, int src_stride, u16* __restrict__ dst,
    const float* __restrict__ cosT, const float* __restrict__ sinT,
    int hshift, float scale)
{
    const int tid = threadIdx.x;
    const int vec = blockIdx.x * 16 + (tid >> 4);   // = m*heads + h
    const int idx = tid & 15;
    const int heads = 1 << hshift;
    const int m = vec >> hshift;
    const int hh = vec & (heads - 1);
    const int t = m & (T_ - 1);
    const int bb = m >> 11;
    const float4 v4 = *(const float4*)(src + (size_t)m * src_stride + hh * 64 + idx * 4);
    const float4 c4 = *(const float4*)(cosT + t * 32 + (idx & 7) * 4);
    const float4 s4 = *(const float4*)(sinT + t * 32 + (idx & 7) * 4);
    const float p0 = __shfl_xor(v4.x, 8);
    const float p1 = __shfl_xor(v4.y, 8);
    const float p2 = __shfl_xor(v4.z, 8);
    const float p3 = __shfl_xor(v4.w, 8);
    float r0, r1, r2, r3;
    if (idx < 8) {
        r0 = fmaf(v4.x, c4.x, p0 * s4.x); r1 = fmaf(v4.y, c4.y, p1 * s4.y);
        r2 = fmaf(v4.z, c4.z, p2 * s4.z); r3 = fmaf(v4.w, c4.w, p3 * s4.w);
    } else {
        r0 = fmaf(v4.x, c4.x, -p0 * s4.x); r1 = fmaf(v4.y, c4.y, -p1 * s4.y);
        r2 = fmaf(v4.z, c4.z, -p2 * s4.z); r3 = fmaf(v4.w, c4.w, -p3 * s4.w);
    }
    float ss = fmaf(r0, r0, fmaf(r1, r1, fmaf(r2, r2, r3 * r3)));
    ss += __shfl_xor(ss, 1);
    ss += __shfl_xor(ss, 2);
    ss += __shfl_xor(ss, 4);
    ss += __shfl_xor(ss, 8);
    const float sc = rsqrtf(ss * (1.0f / HD_) + EPS_) * scale;
    u16x4 o = { f2bf(r0 * sc), f2bf(r1 * sc), f2bf(r2 * sc), f2bf(r3 * sc) };
    *(u16x4*)(dst + ((size_t)(bb * heads + hh) * T_ + t) * HD_ + idx * 4) = o;
}

// ===================== MFMA flash attention v7 (R19-proven: balanced grid) ============
// bid = (15-qblk)*64 + b*16 + h; per-tile math R12-lineage (elementwise mask; branchy
// form BANNED: R9/R10). LDS staging REQUIRED (R13). Truncating P pack (R18-proven).
__global__ __launch_bounds__(512) void attn_mfma_kernel(
    const u16* __restrict__ qb, const u16* __restrict__ kb,
    const u16* __restrict__ vbT, const float* __restrict__ hm,
    u16* __restrict__ yb)
{
    __shared__ __align__(16) u16 Ks[64 * 72];
    __shared__ __align__(16) u16 Vt[64 * 72];
    __shared__ __align__(16) u16 Ps[8 * 16 * 72];
    const int bid = blockIdx.x;
    const int qblk = 15 - (bid >> 6);          // HIGH bits; reversed: longest first
    const int b = (bid >> 4) & 3;
    const int h = bid & 15;
    const int kv = h >> 1;
    const int tid = threadIdx.x;
    const int lane = tid & 63;
    const int w = tid >> 6;                    // 0..7
    const int lr = lane & 15;
    const int lg = lane >> 4;
    const int q0 = qblk * 128;
    const int qt_max = 2 * qblk + 1;

    bf16x8 qf[2];
    {
        const u16* src = qb + ((size_t)(b * NH_ + h) * T_ + q0 + w * 16 + lr) * HD_ + lg * 8;
        qf[0] = *(const bf16x8*)(src);
        qf[1] = *(const bf16x8*)(src + 32);
    }
    f32x4 yacc[4];
    #pragma unroll
    for (int dt = 0; dt < 4; ++dt) yacc[dt] = f32x4{0.f, 0.f, 0.f, 0.f};
    float m = -1e30f, l = 0.f;

    const u16* kbase = kb + (size_t)(b * NKV_ + kv) * T_ * HD_;            // head-major [t][64]
    const u16* vbase = vbT + ((size_t)(b * NKV_) + kv) * (size_t)HD_ * T_; // [d][t]
    u16* Pw = Ps + w * 16 * 72;
    const int qrow_g = q0 + w * 16 + lr;

    const int a0 = tid >> 3, g0 = tid & 7;
    bf16x8 kreg, vreg;
    auto LOADT = [&](int kt) {
        kreg = *(const bf16x8*)(kbase + (size_t)(kt * 64 + a0) * HD_ + g0 * 8);
        vreg = *(const bf16x8*)(vbase + (size_t)a0 * T_ + kt * 64 + g0 * 8);
    };
    auto WRITET = [&]() {
        *(bf16x8*)&Ks[a0 * 72 + g0 * 8] = kreg;
        *(bf16x8*)&Vt[a0 * 72 + g0 * 8] = vreg;
    };

    LOADT(0);
    WRITET();
    for (int kt = 0; kt <= qt_max; ++kt) {
        __syncthreads();                       // tile kt visible in LDS
        if (kt < qt_max) LOADT(kt + 1);        // prefetch next tile into regs
        const int rel = q0 + w * 16 + 15 - kt * 64;
        if (rel >= 0) {                        // wave-uniform skip of fully-masked tiles
            const int mtmax = min(3, rel >> 4);
            f32x4 st[4];
            #pragma unroll
            for (int mt = 0; mt < 4; ++mt) st[mt] = f32x4{0.f, 0.f, 0.f, 0.f};
            __builtin_amdgcn_s_setprio(1);
            #pragma unroll
            for (int mt = 0; mt < 4; ++mt) {
                if (mt <= mtmax) {
                    bf16x8 kf0 = *(const bf16x8*)&Ks[(mt * 16 + lr) * 72 + lg * 8];
                    bf16x8 kf1 = *(const bf16x8*)&Ks[(mt * 16 + lr) * 72 + lg * 8 + 32];
                    st[mt] = __builtin_amdgcn_mfma_f32_16x16x32_bf16(kf0, qf[0], st[mt], 0, 0, 0);
                    st[mt] = __builtin_amdgcn_mfma_f32_16x16x32_bf16(kf1, qf[1], st[mt], 0, 0, 0);
                }
            }
            __builtin_amdgcn_s_setprio(0);
            // mask + per-q max (elementwise PROVEN form)
            float smax = -1e30f;
            #pragma unroll
            for (int mt = 0; mt < 4; ++mt) {
                #pragma unroll
                for (int r = 0; r < 4; ++r) {
                    int keyg = kt * 64 + mt * 16 + lg * 4 + r;
                    float s = (mt <= mtmax && keyg <= qrow_g) ? st[mt][r] : -1e30f;
                    st[mt][r] = s;
                    smax = fmaxf(smax, s);
                }
            }
            smax = fmaxf(smax, __shfl_xor(smax, 16));
            smax = fmaxf(smax, __shfl_xor(smax, 32));
            if (!__all(smax <= m + 8.f)) {     // defer-max: P bounded by 2^8, bf16-safe
                const float mnew = fmaxf(m, smax);
                const float corr = fast_exp2(m - mnew);
                l *= corr;
                float cr[4];
                #pragma unroll
                for (int r = 0; r < 4; ++r) cr[r] = __shfl(corr, lg * 4 + r);
                #pragma unroll
                for (int dt = 0; dt < 4; ++dt)
                    #pragma unroll
                    for (int r = 0; r < 4; ++r) yacc[dt][r] *= cr[r];
                m = mnew;
            }
            float psum = 0.f;
            #pragma unroll
            for (int mt = 0; mt < 4; ++mt) {
                float p0 = fast_exp2(st[mt][0] - m);
                float p1 = fast_exp2(st[mt][1] - m);
                float p2 = fast_exp2(st[mt][2] - m);
                float p3 = fast_exp2(st[mt][3] - m);
                psum += (p0 + p1) + (p2 + p3);
                u16x4 pk = { f2bf_t(p0), f2bf_t(p1), f2bf_t(p2), f2bf_t(p3) };
                *(u16x4*)&Pw[lr * 72 + mt * 16 + lg * 4] = pk;
            }
            psum += __shfl_xor(psum, 16);
            psum += __shfl_xor(psum, 32);
            l += psum;
            // PV: Y[q][d] += P[q][s] * V[s][d]
            const int kimax = min(1, rel >> 5);
            __builtin_amdgcn_s_setprio(1);
            #pragma unroll
            for (int ki = 0; ki < 2; ++ki) {
                if (ki <= kimax) {
                    bf16x8 pf = *(const bf16x8*)&Pw[lr * 72 + ki * 32 + lg * 8];
                    #pragma unroll
                    for (int dt = 0; dt < 4; ++dt) {
                        bf16x8 vf = *(const bf16x8*)&Vt[(dt * 16 + lr) * 72 + ki * 32 + lg * 8];
                        yacc[dt] = __builtin_amdgcn_mfma_f32_16x16x32_bf16(pf, vf, yacc[dt], 0, 0, 0);
                    }
                }
            }
            __builtin_amdgcn_s_setprio(0);
        }
        __syncthreads();                       // all waves done reading tile kt
        if (kt < qt_max) WRITET();             // overwrite LDS with tile kt+1
    }
    const float linv = 1.f / l;
    #pragma unroll
    for (int r = 0; r < 4; ++r) {
        const float lrv = __shfl(linv, lg * 4 + r);
        const int t = q0 + w * 16 + lg * 4 + r;
        const float hmv = hm[((size_t)(b * T_) + t) * NH_ + h];
        const float sc = lrv * hmv;
        #pragma unroll
        for (int dt = 0; dt < 4; ++dt)
            yb[(((size_t)(b * T_) + t) * NH_ + h) * HD_ + dt * 16 + lr] = f2bf(yacc[dt][r] * sc);
    }
}

extern "C" void kernel_launch(void* const* d_in, const int* in_sizes, int n_in,
                              void* d_out, int out_size, void* d_ws, size_t ws_size,
                              hipStream_t stream) {
    const float* x    = (const float*)d_in[0];
    const float* ve   = (const float*)d_in[1];
    const float* cosT = (const float*)d_in[2];
    const float* sinT = (const float*)d_in[3];
    const float* Wq   = (const float*)d_in[4];
    const float* Wk   = (const float*)d_in[5];
    const float* Wv   = (const float*)d_in[6];
    const float* Wo   = (const float*)d_in[7];
    const float* Wr   = (const float*)d_in[8];
    const float* Wg   = (const float*)d_in[9];
    float* out = (float*)d_out;
    float* hm  = out + (size_t)B_ * T_ * C_;

    const int M = B_ * T_;  // 8192
    float* ws = (float*)d_ws;
    float* qf32  = ws;                  // 8388608 f   [after rope_q: yb bf16]
    float* kf32  = qf32 + 8388608;      // 4194304 f
    float* xbr   = kf32 + 4194304;      // 4194304 f (bf16 x) [after QKV gemm: qb bf16]
    float* wqkvr = xbr + 4194304;       // 1048576 f (bf16 Wqkv)
    float* wor   = wqkvr + 1048576;     // 524288 f  (bf16 Wo)
    float* gate  = wor + 524288;        // 65536 f
    float* vtr   = gate + 65536;        // 2097152 f (bf16 vT [b][kv][d][t], from GEMM)
    float* kbr   = vtr + 2097152;       // 2097152 f (bf16 k roped, head-major)

    u16* xb    = (u16*)xbr;
    u16* Wqkvb = (u16*)wqkvr;
    u16* Wob   = (u16*)wor;
    u16* vbT   = (u16*)vtr;
    u16* qb    = (u16*)xbr;    // overlays xb (dead after QKV GEMM), head-major
    u16* kb    = (u16*)kbr;    // head-major
    u16* yb    = (u16*)qf32;   // overlays qf32 (dead after rope_q)

    // ---- weight casts ----
    cast_weights_kernel<<<3072, 256, 0, stream>>>(Wq, Wk, Wv, Wo, Wqkvb, Wob);
    // ---- router (gate feeds the fused V epilogue; also emits xb) ----
    logits_mask_gate_kernel<<<M, 64, 0, stream>>>(x, Wr, Wg, hm, gate, xb);
    // ---- fused QKV projection (256x256 tile, 128x64 wave tile; v written as vbT) ----
    gemm_qkv_256x256<<<dim3(2048 / 256, M / 256), 512, 0, stream>>>(
        xb, Wqkvb, M, C_, qf32, kf32, vbT, gate, ve);
    // ---- rope+rms -> bf16 head-major (q folded with 1/sqrt(HD)*log2e for exp2 softmax) ----
    rope_rms_kernel<<<(M * NH_) / 16, 256, 0, stream>>>(qf32, 1024, qb, cosT, sinT, 4, 0.125f * LOG2E_);
    rope_rms_kernel<<<(M * NKV_) / 16, 256, 0, stream>>>(kf32, 512, kb, cosT, sinT, 3, 1.0f);
    // ---- flash attention (QBLK=128, 8 waves; balanced grid) ----
    attn_mfma_kernel<<<B_ * NH_ * (T_ / 128), 512, 0, stream>>>(qb, kb, vbT, hm, yb);
    // ---- output projection (R16 256x128 pipeline) ----
    gemm_bf16_256<0><<<dim3(C_ / 128, M / 256), 512, 0, stream>>>(
        yb, Wob, out, M, C_, C_);
}

// Round 21
// 222.522 us; speedup vs baseline: 1.1561x; 1.1561x over previous
//
#include <hip/hip_runtime.h>
#include <math.h>

#define B_ 4
#define T_ 2048
#define C_ 1024
#define NH_ 16
#define NKV_ 8
#define HD_ 64
#define KACT_ 8
#define VG_ 32
#define EPS_ 1e-6f
#define LOG2E_ 1.44269504088896340736f

typedef __attribute__((ext_vector_type(8))) short bf16x8;
typedef __attribute__((ext_vector_type(4))) float f32x4;
typedef __attribute__((ext_vector_type(4))) unsigned short u16x4;
typedef unsigned short u16;
typedef unsigned int u32;

__device__ inline u16 f2bf(float f) {
    u32 u = __float_as_uint(f);
    u += 0x7fffu + ((u >> 16) & 1u);   // RNE (finite data)
    return (u16)(u >> 16);
}

__device__ inline u16 f2bf_t(float f) {        // truncating (P>=0 softmax weights only)
    return (u16)(__float_as_uint(f) >> 16);
}

__device__ inline float fast_exp2(float x) {   // bare v_exp_f32 (D = 2^S0), no libm guards
    float r;
    asm("v_exp_f32 %0, %1" : "=v"(r) : "v"(x));
    return r;
}

__device__ inline void gload_lds16(const void* g, void* s) {
    __builtin_amdgcn_global_load_lds((const __attribute__((address_space(1))) void*)g,
                                     (__attribute__((address_space(3))) void*)s, 16, 0, 0);
}

__device__ inline void bar() {                 // raw barrier + compiler memory fence
    asm volatile("" ::: "memory");
    __builtin_amdgcn_s_barrier();
    asm volatile("" ::: "memory");
}

// st_16x32 swizzle (involution): byte ^= ((byte>>9)&1)<<5 within a 16KB [128][64]bf16 unit
__device__ inline int swz(int b) { return b ^ (((b >> 9) & 1) << 5); }

// ===================== fused weight casts: Wq|Wk|Wv -> wqkv, Wo -> wo =====================
__global__ __launch_bounds__(256) void cast_weights_kernel(
    const float* __restrict__ Wq, const float* __restrict__ Wk,
    const float* __restrict__ Wv, const float* __restrict__ Wo,
    u16* __restrict__ wqkv, u16* __restrict__ wo)
{
    int i = blockIdx.x * 256 + threadIdx.x;    // 786432 float4 chunks total
    const float* src; u16* dst; int j;
    if (i < 262144)      { src = Wq; dst = wqkv;           j = i; }
    else if (i < 393216) { src = Wk; dst = wqkv + 1048576; j = i - 262144; }
    else if (i < 524288) { src = Wv; dst = wqkv + 1572864; j = i - 393216; }
    else                 { src = Wo; dst = wo;             j = i - 524288; }
    float4 v = ((const float4*)src)[j];
    u16x4 o = { f2bf(v.x), f2bf(v.y), f2bf(v.z), f2bf(v.w) };
    ((u16x4*)dst)[j] = o;
}

// ===================== bf16 NT-GEMM: 256x128 tile, counted-vmcnt pipeline (R16-proven) ==
// Out = A(MxK) * W(NxK)^T. BK=64, 512 threads = 8 waves (2M x 4N), wave tile 128x32.
// A triple-buffered (stage kt+2), B double-buffered (stage kt+1). vmcnt(4) at K-tile
// entry; vmcnt(0) only at the last K-tile. T4 counted-vmcnt keeps loads in flight
// ACROSS barriers — R20 proved this is worth more than a bigger tile (256x256 w/
// vmcnt(0) drains: 86->118us regression). st_16x32 swizzle involution on source chunk
// + read byte. K order identical to R2 kernel -> bit-identical accumulators.
// MODE 0: plain f32 Out. MODE 1: fused QKV epilogue:
//   q f32 token-major; k f32 token-major; v -> gate*ve add, bf16, written DIRECTLY
//   transposed as vbT[b][kv][d][t] (4 consecutive tokens per thread = packed 8B store).
template<int MODE>
__global__ __launch_bounds__(512) void gemm_bf16_256(
    const u16* __restrict__ A, const u16* __restrict__ W,
    float* __restrict__ Out, int M, int N, int K,
    float* __restrict__ q_out, float* __restrict__ k_out, u16* __restrict__ vT_out,
    const float* __restrict__ gate, const float* __restrict__ ve)
{
    __shared__ __align__(16) u16 AL[3][2][128 * 64];   // 96 KB
    __shared__ __align__(16) u16 BL[2][128 * 64];      // 32 KB
    const int tid = threadIdx.x;
    const int lane = tid & 63;
    const int w = tid >> 6;
    const int bm = blockIdx.y * 256;
    const int bn = blockIdx.x * 128;
    const int wm = (w >> 2) * 128;     // A half = w>>2
    const int wn = (w & 3) * 32;
    const int ah = w >> 2;
    const int lr = lane & 15, lg = lane >> 4;
    const int NKT = K >> 6;            // 16

    f32x4 acc[8][2];
    #pragma unroll
    for (int mi = 0; mi < 8; ++mi)
        #pragma unroll
        for (int ni = 0; ni < 2; ++ni) acc[mi][ni] = f32x4{0.f, 0.f, 0.f, 0.f};

    auto stageA = [&](int kt) {        // both halves, 4 loads FIFO
        const int db = kt % 3;
        #pragma unroll
        for (int hf = 0; hf < 2; ++hf)
            #pragma unroll
            for (int ci = 0; ci < 2; ++ci) {
                int c = tid + ci * 512;
                int l = c ^ (((c >> 5) & 1) << 1);
                gload_lds16(A + (size_t)(bm + hf * 128 + (l >> 3)) * K + kt * 64 + (l & 7) * 8,
                            (char*)&AL[db][hf][0] + c * 16);
            }
    };
    auto stageB = [&](int kt) {        // 2 loads
        const int db = kt & 1;
        #pragma unroll
        for (int ci = 0; ci < 2; ++ci) {
            int c = tid + ci * 512;
            int l = c ^ (((c >> 5) & 1) << 1);
            gload_lds16(W + (size_t)(bn + (l >> 3)) * K + kt * 64 + (l & 7) * 8,
                        (char*)&BL[db][0] + c * 16);
        }
    };

    stageA(0);
    stageB(0);
    stageA(1);                          // FIFO: [A0(4), B0(2), A1(4)]

    for (int kt = 0; kt < NKT; ++kt) {
        const int ab = kt % 3, bb = kt & 1;
        if (kt == NKT - 1) asm volatile("s_waitcnt vmcnt(0)" ::: "memory");
        else               asm volatile("s_waitcnt vmcnt(4)" ::: "memory");
        bar();                          // all waves' loads for K-tile kt landed
        #pragma unroll
        for (int ph = 0; ph < 2; ++ph) {
            bf16x8 af[4][2], bfm[2][2];
            #pragma unroll
            for (int mi2 = 0; mi2 < 4; ++mi2) {
                const int row = (ph * 4 + mi2) * 16 + lr;
                #pragma unroll
                for (int kk = 0; kk < 2; ++kk)
                    af[mi2][kk] = *(const bf16x8*)((const char*)&AL[ab][ah][0] +
                                                   swz(row * 128 + kk * 64 + lg * 16));
            }
            #pragma unroll
            for (int ni = 0; ni < 2; ++ni) {
                const int row = wn + ni * 16 + lr;
                #pragma unroll
                for (int kk = 0; kk < 2; ++kk)
                    bfm[ni][kk] = *(const bf16x8*)((const char*)&BL[bb][0] +
                                                   swz(row * 128 + kk * 64 + lg * 16));
            }
            if (ph == 0) { if (kt + 1 < NKT) stageB(kt + 1); }
            else         { if (kt + 2 < NKT) stageA(kt + 2); }
            bar();
            __builtin_amdgcn_s_setprio(1);
            #pragma unroll
            for (int mi2 = 0; mi2 < 4; ++mi2)
                #pragma unroll
                for (int ni = 0; ni < 2; ++ni)
                    #pragma unroll
                    for (int kk = 0; kk < 2; ++kk)
                        acc[ph * 4 + mi2][ni] = __builtin_amdgcn_mfma_f32_16x16x32_bf16(
                            af[mi2][kk], bfm[ni][kk], acc[ph * 4 + mi2][ni], 0, 0, 0);
            __builtin_amdgcn_s_setprio(0);
            bar();
        }
    }

    #pragma unroll
    for (int mi = 0; mi < 8; ++mi)
        #pragma unroll
        for (int ni = 0; ni < 2; ++ni) {
            const int row0 = bm + wm + mi * 16 + lg * 4;   // 4 consecutive tokens, same b
            const int col = bn + wn + ni * 16 + lr;
            if (MODE == 0) {
                #pragma unroll
                for (int r = 0; r < 4; ++r)
                    Out[(size_t)(row0 + r) * N + col] = acc[mi][ni][r];
            } else {
                if (col < 1024) {
                    #pragma unroll
                    for (int r = 0; r < 4; ++r)
                        q_out[(size_t)(row0 + r) * 1024 + col] = acc[mi][ni][r];
                } else if (col < 1536) {
                    #pragma unroll
                    for (int r = 0; r < 4; ++r)
                        k_out[(size_t)(row0 + r) * 512 + (col - 1024)] = acc[mi][ni][r];
                } else {
                    const int cc = col - 1536;
                    const int kv = cc >> 6, d = cc & 63;
                    u16x4 pk;
                    #pragma unroll
                    for (int r = 0; r < 4; ++r) {
                        const int row = row0 + r;
                        pk[r] = f2bf(acc[mi][ni][r] +
                                     gate[row * NKV_ + kv] * ve[(size_t)row * 512 + cc]);
                    }
                    *(u16x4*)(vT_out + ((size_t)((row0 >> 11) * NKV_ + kv) * HD_ + d) * T_ +
                              (row0 & (T_ - 1))) = pk;
                }
            }
        }
}

// ===================== Router + top-8 mask + gate + fused x->bf16 cast (R12-proven) ====
__global__ __launch_bounds__(64) void logits_mask_gate_kernel(
    const float* __restrict__ x, const float* __restrict__ Wr,
    const float* __restrict__ Wg, float* __restrict__ hm, float* __restrict__ gate,
    u16* __restrict__ xb)
{
    const int token = blockIdx.x;
    const int lane = threadIdx.x;
    const float* xr = x + (size_t)token * C_;
    __shared__ float lg[NH_];
    __shared__ float thr_s;
    float part[NH_];
    #pragma unroll
    for (int h = 0; h < NH_; ++h) part[h] = 0.f;
    for (int c = lane; c < C_; c += 64) {
        float xv = xr[c];
        xb[(size_t)token * C_ + c] = f2bf(xv);   // fused cast
        #pragma unroll
        for (int h = 0; h < NH_; ++h) part[h] = fmaf(xv, Wr[h * C_ + c], part[h]);
    }
    #pragma unroll
    for (int h = 0; h < NH_; ++h) {
        float s = part[h];
        #pragma unroll
        for (int off = 32; off; off >>= 1) s += __shfl_xor(s, off);
        if (lane == 0) lg[h] = s;
    }
    __syncthreads();
    if (lane == 0) {
        unsigned used = 0;
        float last = 0.f;
        for (int p = 0; p < KACT_; ++p) {
            float bv = -3.4e38f; int bi = 0;
            for (int i = 0; i < NH_; ++i)
                if (!(used & (1u << i)) && lg[i] > bv) { bv = lg[i]; bi = i; }
            used |= 1u << bi;
            last = bv;
        }
        thr_s = last;
    }
    __syncthreads();
    if (lane < NH_) hm[(size_t)token * NH_ + lane] = (lg[lane] >= thr_s) ? 1.f : 0.f;
    if (lane < NKV_) {
        float s = 0.f;
        #pragma unroll
        for (int g = 0; g < VG_; ++g) s = fmaf(xr[g], Wg[lane * VG_ + g], s);
        gate[(size_t)token * NKV_ + lane] = 2.f / (1.f + __expf(-s));
    }
}

// ===================== rotary + rms-norm, 16-vec/block, HEAD-major out (R7-proven) ====
__global__ __launch_bounds__(256) void rope_rms_kernel(
    const float* __restrict__ src, int src_stride, u16* __restrict__ dst,
    const float* __restrict__ cosT, const float* __restrict__ sinT,
    int hshift, float scale)
{
    const int tid = threadIdx.x;
    const int vec = blockIdx.x * 16 + (tid >> 4);   // = m*heads + h
    const int idx = tid & 15;
    const int heads = 1 << hshift;
    const int m = vec >> hshift;
    const int hh = vec & (heads - 1);
    const int t = m & (T_ - 1);
    const int bb = m >> 11;
    const float4 v4 = *(const float4*)(src + (size_t)m * src_stride + hh * 64 + idx * 4);
    const float4 c4 = *(const float4*)(cosT + t * 32 + (idx & 7) * 4);
    const float4 s4 = *(const float4*)(sinT + t * 32 + (idx & 7) * 4);
    const float p0 = __shfl_xor(v4.x, 8);
    const float p1 = __shfl_xor(v4.y, 8);
    const float p2 = __shfl_xor(v4.z, 8);
    const float p3 = __shfl_xor(v4.w, 8);
    float r0, r1, r2, r3;
    if (idx < 8) {
        r0 = fmaf(v4.x, c4.x, p0 * s4.x); r1 = fmaf(v4.y, c4.y, p1 * s4.y);
        r2 = fmaf(v4.z, c4.z, p2 * s4.z); r3 = fmaf(v4.w, c4.w, p3 * s4.w);
    } else {
        r0 = fmaf(v4.x, c4.x, -p0 * s4.x); r1 = fmaf(v4.y, c4.y, -p1 * s4.y);
        r2 = fmaf(v4.z, c4.z, -p2 * s4.z); r3 = fmaf(v4.w, c4.w, -p3 * s4.w);
    }
    float ss = fmaf(r0, r0, fmaf(r1, r1, fmaf(r2, r2, r3 * r3)));
    ss += __shfl_xor(ss, 1);
    ss += __shfl_xor(ss, 2);
    ss += __shfl_xor(ss, 4);
    ss += __shfl_xor(ss, 8);
    const float sc = rsqrtf(ss * (1.0f / HD_) + EPS_) * scale;
    u16x4 o = { f2bf(r0 * sc), f2bf(r1 * sc), f2bf(r2 * sc), f2bf(r3 * sc) };
    *(u16x4*)(dst + ((size_t)(bb * heads + hh) * T_ + t) * HD_ + idx * 4) = o;
}

// ===================== MFMA flash attention v7 (R19-proven: balanced grid) ============
// bid = (15-qblk)*64 + b*16 + h; per-tile math R12-lineage (elementwise mask; branchy
// form BANNED: R9/R10). LDS staging REQUIRED (R13). Truncating P pack (R18-proven).
__global__ __launch_bounds__(512) void attn_mfma_kernel(
    const u16* __restrict__ qb, const u16* __restrict__ kb,
    const u16* __restrict__ vbT, const float* __restrict__ hm,
    u16* __restrict__ yb)
{
    __shared__ __align__(16) u16 Ks[64 * 72];
    __shared__ __align__(16) u16 Vt[64 * 72];
    __shared__ __align__(16) u16 Ps[8 * 16 * 72];
    const int bid = blockIdx.x;
    const int qblk = 15 - (bid >> 6);          // HIGH bits; reversed: longest first
    const int b = (bid >> 4) & 3;
    const int h = bid & 15;
    const int kv = h >> 1;
    const int tid = threadIdx.x;
    const int lane = tid & 63;
    const int w = tid >> 6;                    // 0..7
    const int lr = lane & 15;
    const int lg = lane >> 4;
    const int q0 = qblk * 128;
    const int qt_max = 2 * qblk + 1;

    bf16x8 qf[2];
    {
        const u16* src = qb + ((size_t)(b * NH_ + h) * T_ + q0 + w * 16 + lr) * HD_ + lg * 8;
        qf[0] = *(const bf16x8*)(src);
        qf[1] = *(const bf16x8*)(src + 32);
    }
    f32x4 yacc[4];
    #pragma unroll
    for (int dt = 0; dt < 4; ++dt) yacc[dt] = f32x4{0.f, 0.f, 0.f, 0.f};
    float m = -1e30f, l = 0.f;

    const u16* kbase = kb + (size_t)(b * NKV_ + kv) * T_ * HD_;            // head-major [t][64]
    const u16* vbase = vbT + ((size_t)(b * NKV_) + kv) * (size_t)HD_ * T_; // [d][t]
    u16* Pw = Ps + w * 16 * 72;
    const int qrow_g = q0 + w * 16 + lr;

    const int a0 = tid >> 3, g0 = tid & 7;
    bf16x8 kreg, vreg;
    auto LOADT = [&](int kt) {
        kreg = *(const bf16x8*)(kbase + (size_t)(kt * 64 + a0) * HD_ + g0 * 8);
        vreg = *(const bf16x8*)(vbase + (size_t)a0 * T_ + kt * 64 + g0 * 8);
    };
    auto WRITET = [&]() {
        *(bf16x8*)&Ks[a0 * 72 + g0 * 8] = kreg;
        *(bf16x8*)&Vt[a0 * 72 + g0 * 8] = vreg;
    };

    LOADT(0);
    WRITET();
    for (int kt = 0; kt <= qt_max; ++kt) {
        __syncthreads();                       // tile kt visible in LDS
        if (kt < qt_max) LOADT(kt + 1);        // prefetch next tile into regs
        const int rel = q0 + w * 16 + 15 - kt * 64;
        if (rel >= 0) {                        // wave-uniform skip of fully-masked tiles
            const int mtmax = min(3, rel >> 4);
            f32x4 st[4];
            #pragma unroll
            for (int mt = 0; mt < 4; ++mt) st[mt] = f32x4{0.f, 0.f, 0.f, 0.f};
            __builtin_amdgcn_s_setprio(1);
            #pragma unroll
            for (int mt = 0; mt < 4; ++mt) {
                if (mt <= mtmax) {
                    bf16x8 kf0 = *(const bf16x8*)&Ks[(mt * 16 + lr) * 72 + lg * 8];
                    bf16x8 kf1 = *(const bf16x8*)&Ks[(mt * 16 + lr) * 72 + lg * 8 + 32];
                    st[mt] = __builtin_amdgcn_mfma_f32_16x16x32_bf16(kf0, qf[0], st[mt], 0, 0, 0);
                    st[mt] = __builtin_amdgcn_mfma_f32_16x16x32_bf16(kf1, qf[1], st[mt], 0, 0, 0);
                }
            }
            __builtin_amdgcn_s_setprio(0);
            // mask + per-q max (elementwise PROVEN form)
            float smax = -1e30f;
            #pragma unroll
            for (int mt = 0; mt < 4; ++mt) {
                #pragma unroll
                for (int r = 0; r < 4; ++r) {
                    int keyg = kt * 64 + mt * 16 + lg * 4 + r;
                    float s = (mt <= mtmax && keyg <= qrow_g) ? st[mt][r] : -1e30f;
                    st[mt][r] = s;
                    smax = fmaxf(smax, s);
                }
            }
            smax = fmaxf(smax, __shfl_xor(smax, 16));
            smax = fmaxf(smax, __shfl_xor(smax, 32));
            if (!__all(smax <= m + 8.f)) {     // defer-max: P bounded by 2^8, bf16-safe
                const float mnew = fmaxf(m, smax);
                const float corr = fast_exp2(m - mnew);
                l *= corr;
                float cr[4];
                #pragma unroll
                for (int r = 0; r < 4; ++r) cr[r] = __shfl(corr, lg * 4 + r);
                #pragma unroll
                for (int dt = 0; dt < 4; ++dt)
                    #pragma unroll
                    for (int r = 0; r < 4; ++r) yacc[dt][r] *= cr[r];
                m = mnew;
            }
            float psum = 0.f;
            #pragma unroll
            for (int mt = 0; mt < 4; ++mt) {
                float p0 = fast_exp2(st[mt][0] - m);
                float p1 = fast_exp2(st[mt][1] - m);
                float p2 = fast_exp2(st[mt][2] - m);
                float p3 = fast_exp2(st[mt][3] - m);
                psum += (p0 + p1) + (p2 + p3);
                u16x4 pk = { f2bf_t(p0), f2bf_t(p1), f2bf_t(p2), f2bf_t(p3) };
                *(u16x4*)&Pw[lr * 72 + mt * 16 + lg * 4] = pk;
            }
            psum += __shfl_xor(psum, 16);
            psum += __shfl_xor(psum, 32);
            l += psum;
            // PV: Y[q][d] += P[q][s] * V[s][d]
            const int kimax = min(1, rel >> 5);
            __builtin_amdgcn_s_setprio(1);
            #pragma unroll
            for (int ki = 0; ki < 2; ++ki) {
                if (ki <= kimax) {
                    bf16x8 pf = *(const bf16x8*)&Pw[lr * 72 + ki * 32 + lg * 8];
                    #pragma unroll
                    for (int dt = 0; dt < 4; ++dt) {
                        bf16x8 vf = *(const bf16x8*)&Vt[(dt * 16 + lr) * 72 + ki * 32 + lg * 8];
                        yacc[dt] = __builtin_amdgcn_mfma_f32_16x16x32_bf16(pf, vf, yacc[dt], 0, 0, 0);
                    }
                }
            }
            __builtin_amdgcn_s_setprio(0);
        }
        __syncthreads();                       // all waves done reading tile kt
        if (kt < qt_max) WRITET();             // overwrite LDS with tile kt+1
    }
    const float linv = 1.f / l;
    #pragma unroll
    for (int r = 0; r < 4; ++r) {
        const float lrv = __shfl(linv, lg * 4 + r);
        const int t = q0 + w * 16 + lg * 4 + r;
        const float hmv = hm[((size_t)(b * T_) + t) * NH_ + h];
        const float sc = lrv * hmv;
        #pragma unroll
        for (int dt = 0; dt < 4; ++dt)
            yb[(((size_t)(b * T_) + t) * NH_ + h) * HD_ + dt * 16 + lr] = f2bf(yacc[dt][r] * sc);
    }
}

extern "C" void kernel_launch(void* const* d_in, const int* in_sizes, int n_in,
                              void* d_out, int out_size, void* d_ws, size_t ws_size,
                              hipStream_t stream) {
    const float* x    = (const float*)d_in[0];
    const float* ve   = (const float*)d_in[1];
    const float* cosT = (const float*)d_in[2];
    const float* sinT = (const float*)d_in[3];
    const float* Wq   = (const float*)d_in[4];
    const float* Wk   = (const float*)d_in[5];
    const float* Wv   = (const float*)d_in[6];
    const float* Wo   = (const float*)d_in[7];
    const float* Wr   = (const float*)d_in[8];
    const float* Wg   = (const float*)d_in[9];
    float* out = (float*)d_out;
    float* hm  = out + (size_t)B_ * T_ * C_;

    const int M = B_ * T_;  // 8192
    float* ws = (float*)d_ws;
    float* qf32  = ws;                  // 8388608 f   [after rope_q: yb bf16]
    float* kf32  = qf32 + 8388608;      // 4194304 f
    float* xbr   = kf32 + 4194304;      // 4194304 f (bf16 x) [after QKV gemm: qb bf16]
    float* wqkvr = xbr + 4194304;       // 1048576 f (bf16 Wqkv)
    float* wor   = wqkvr + 1048576;     // 524288 f  (bf16 Wo)
    float* gate  = wor + 524288;        // 65536 f
    float* vtr   = gate + 65536;        // 2097152 f (bf16 vT [b][kv][d][t], from GEMM)
    float* kbr   = vtr + 2097152;       // 2097152 f (bf16 k roped, head-major)

    u16* xb    = (u16*)xbr;
    u16* Wqkvb = (u16*)wqkvr;
    u16* Wob   = (u16*)wor;
    u16* vbT   = (u16*)vtr;
    u16* qb    = (u16*)xbr;    // overlays xb (dead after QKV GEMM), head-major
    u16* kb    = (u16*)kbr;    // head-major
    u16* yb    = (u16*)qf32;   // overlays qf32 (dead after rope_q)

    // ---- weight casts ----
    cast_weights_kernel<<<3072, 256, 0, stream>>>(Wq, Wk, Wv, Wo, Wqkvb, Wob);
    // ---- router (gate feeds the fused V epilogue; also emits xb) ----
    logits_mask_gate_kernel<<<M, 64, 0, stream>>>(x, Wr, Wg, hm, gate, xb);
    // ---- fused QKV projection (256x128 counted-vmcnt pipeline; v written as vbT) ----
    gemm_bf16_256<1><<<dim3(2048 / 128, M / 256), 512, 0, stream>>>(
        xb, Wqkvb, nullptr, M, 2048, C_, qf32, kf32, vbT, gate, ve);
    // ---- rope+rms -> bf16 head-major (q folded with 1/sqrt(HD)*log2e for exp2 softmax) ----
    rope_rms_kernel<<<(M * NH_) / 16, 256, 0, stream>>>(qf32, 1024, qb, cosT, sinT, 4, 0.125f * LOG2E_);
    rope_rms_kernel<<<(M * NKV_) / 16, 256, 0, stream>>>(kf32, 512, kb, cosT, sinT, 3, 1.0f);
    // ---- flash attention (QBLK=128, 8 waves; balanced grid) ----
    attn_mfma_kernel<<<B_ * NH_ * (T_ / 128), 512, 0, stream>>>(qb, kb, vbT, hm, yb);
    // ---- output projection (R16 256x128 pipeline) ----
    gemm_bf16_256<0><<<dim3(C_ / 128, M / 256), 512, 0, stream>>>(
        yb, Wob, out, M, C_, C_, nullptr, nullptr, nullptr, nullptr, nullptr);
}

// Round 22
// 199.979 us; speedup vs baseline: 1.2864x; 1.1127x over previous
//
#include <hip/hip_runtime.h>
#include <math.h>

#define B_ 4
#define T_ 2048
#define C_ 1024
#define NH_ 16
#define NKV_ 8
#define HD_ 64
#define KACT_ 8
#define VG_ 32
#define EPS_ 1e-6f
#define LOG2E_ 1.44269504088896340736f

typedef __attribute__((ext_vector_type(8))) short bf16x8;
typedef __attribute__((ext_vector_type(4))) float f32x4;
typedef __attribute__((ext_vector_type(4))) unsigned short u16x4;
typedef unsigned short u16;
typedef unsigned int u32;

__device__ inline u16 f2bf(float f) {
    u32 u = __float_as_uint(f);
    u += 0x7fffu + ((u >> 16) & 1u);   // RNE (finite data)
    return (u16)(u >> 16);
}

__device__ inline u16 f2bf_t(float f) {        // truncating (P>=0 softmax weights only)
    return (u16)(__float_as_uint(f) >> 16);
}

__device__ inline float bf2f(u16 u) { return __uint_as_float((u32)u << 16); }

__device__ inline float fast_exp2(float x) {   // bare v_exp_f32 (D = 2^S0), no libm guards
    float r;
    asm("v_exp_f32 %0, %1" : "=v"(r) : "v"(x));
    return r;
}

__device__ inline void gload_lds16(const void* g, void* s) {
    __builtin_amdgcn_global_load_lds((const __attribute__((address_space(1))) void*)g,
                                     (__attribute__((address_space(3))) void*)s, 16, 0, 0);
}

__device__ inline void bar() {                 // raw barrier + compiler memory fence
    asm volatile("" ::: "memory");
    __builtin_amdgcn_s_barrier();
    asm volatile("" ::: "memory");
}

// st_16x32 swizzle (involution) for BK=64 tiles: byte ^= ((byte>>9)&1)<<5
__device__ inline int swz(int b) { return b ^ (((b >> 9) & 1) << 5); }

// ===================== fused weight casts: Wq|Wk|Wv -> wqkv, Wo -> wo =====================
__global__ __launch_bounds__(256) void cast_weights_kernel(
    const float* __restrict__ Wq, const float* __restrict__ Wk,
    const float* __restrict__ Wv, const float* __restrict__ Wo,
    u16* __restrict__ wqkv, u16* __restrict__ wo)
{
    int i = blockIdx.x * 256 + threadIdx.x;    // 786432 float4 chunks total
    const float* src; u16* dst; int j;
    if (i < 262144)      { src = Wq; dst = wqkv;           j = i; }
    else if (i < 393216) { src = Wk; dst = wqkv + 1048576; j = i - 262144; }
    else if (i < 524288) { src = Wv; dst = wqkv + 1572864; j = i - 393216; }
    else                 { src = Wo; dst = wo;             j = i - 524288; }
    float4 v = ((const float4*)src)[j];
    u16x4 o = { f2bf(v.x), f2bf(v.y), f2bf(v.z), f2bf(v.w) };
    ((u16x4*)dst)[j] = o;
}

// ===================== QKV GEMM: 256x128 tile, BK=32, 64KB LDS (2 blocks/CU) ===========
// Same counted-vmcnt FIFO discipline as the R16-proven template, kk-loop removed:
// A triple-buffered (stage kt+2), B double-buffered (stage kt+1); vmcnt(2) at K-tile
// entry (A(kt+1)'s 2 loads stay in flight), vmcnt(0) only at the last tile. 64B rows
// give naturally balanced banks (8 dwords/bank = b128 floor) -> NO swizzle. kt-asc K
// order -> bit-identical accumulators vs BK=64. Epilogue: q,k -> bf16 token-major;
// v -> gate*ve add, bf16, written transposed as vbT[b][kv][d][t].
__global__ __launch_bounds__(512) void gemm_qkv_bk32(
    const u16* __restrict__ A, const u16* __restrict__ W, int M, int K,
    u16* __restrict__ q_out, u16* __restrict__ k_out, u16* __restrict__ vT_out,
    const float* __restrict__ gate, const float* __restrict__ ve)
{
    __shared__ __align__(16) u16 AL[3][2][128 * 32];   // 48 KB
    __shared__ __align__(16) u16 BL[2][128 * 32];      // 16 KB
    const int tid = threadIdx.x;
    const int lane = tid & 63;
    const int w = tid >> 6;
    const int bm = blockIdx.y * 256;
    const int bn = blockIdx.x * 128;
    const int wm = (w >> 2) * 128;
    const int wn = (w & 3) * 32;
    const int ah = w >> 2;
    const int lr = lane & 15, lg = lane >> 4;
    const int NKT = K >> 5;            // 32

    f32x4 acc[8][2];
    #pragma unroll
    for (int mi = 0; mi < 8; ++mi)
        #pragma unroll
        for (int ni = 0; ni < 2; ++ni) acc[mi][ni] = f32x4{0.f, 0.f, 0.f, 0.f};

    // 512 chunks (16B) per 8KB half; thread t covers chunk t. row=c>>2, col16=c&3.
    auto stageA = [&](int kt) {        // 2 loads FIFO (one per half)
        const int db = kt % 3;
        #pragma unroll
        for (int hf = 0; hf < 2; ++hf) {
            int c = tid;
            gload_lds16(A + (size_t)(bm + hf * 128 + (c >> 2)) * K + kt * 32 + (c & 3) * 8,
                        (char*)&AL[db][hf][0] + c * 16);
        }
    };
    auto stageB = [&](int kt) {        // 1 load
        const int db = kt & 1;
        int c = tid;
        gload_lds16(W + (size_t)(bn + (c >> 2)) * K + kt * 32 + (c & 3) * 8,
                    (char*)&BL[db][0] + c * 16);
    };

    stageA(0);
    stageB(0);
    stageA(1);                          // FIFO: [A0(2), B0(1), A1(2)] = 5 outstanding

    for (int kt = 0; kt < NKT; ++kt) {
        const int ab = kt % 3, bb = kt & 1;
        if (kt == NKT - 1) asm volatile("s_waitcnt vmcnt(0)" ::: "memory");
        else               asm volatile("s_waitcnt vmcnt(2)" ::: "memory");
        bar();                          // all waves' loads for K-tile kt landed
        #pragma unroll
        for (int ph = 0; ph < 2; ++ph) {
            bf16x8 af[4], bfm[2];
            #pragma unroll
            for (int mi2 = 0; mi2 < 4; ++mi2) {
                const int row = (ph * 4 + mi2) * 16 + lr;
                af[mi2] = *(const bf16x8*)((const char*)&AL[ab][ah][0] + row * 64 + lg * 16);
            }
            #pragma unroll
            for (int ni = 0; ni < 2; ++ni) {
                const int row = wn + ni * 16 + lr;
                bfm[ni] = *(const bf16x8*)((const char*)&BL[bb][0] + row * 64 + lg * 16);
            }
            if (ph == 0) { if (kt + 1 < NKT) stageB(kt + 1); }
            else         { if (kt + 2 < NKT) stageA(kt + 2); }
            bar();
            __builtin_amdgcn_s_setprio(1);
            #pragma unroll
            for (int mi2 = 0; mi2 < 4; ++mi2)
                #pragma unroll
                for (int ni = 0; ni < 2; ++ni)
                    acc[ph * 4 + mi2][ni] = __builtin_amdgcn_mfma_f32_16x16x32_bf16(
                        af[mi2], bfm[ni], acc[ph * 4 + mi2][ni], 0, 0, 0);
            __builtin_amdgcn_s_setprio(0);
            bar();
        }
    }

    #pragma unroll
    for (int mi = 0; mi < 8; ++mi)
        #pragma unroll
        for (int ni = 0; ni < 2; ++ni) {
            const int row0 = bm + wm + mi * 16 + lg * 4;   // 4 consecutive tokens, same b
            const int col = bn + wn + ni * 16 + lr;
            if (col < 1024) {
                #pragma unroll
                for (int r = 0; r < 4; ++r)
                    q_out[(size_t)(row0 + r) * 1024 + col] = f2bf(acc[mi][ni][r]);
            } else if (col < 1536) {
                #pragma unroll
                for (int r = 0; r < 4; ++r)
                    k_out[(size_t)(row0 + r) * 512 + (col - 1024)] = f2bf(acc[mi][ni][r]);
            } else {
                const int cc = col - 1536;
                const int kv = cc >> 6, d = cc & 63;
                u16x4 pk;
                #pragma unroll
                for (int r = 0; r < 4; ++r) {
                    const int row = row0 + r;
                    pk[r] = f2bf(acc[mi][ni][r] +
                                 gate[row * NKV_ + kv] * ve[(size_t)row * 512 + cc]);
                }
                *(u16x4*)(vT_out + ((size_t)((row0 >> 11) * NKV_ + kv) * HD_ + d) * T_ +
                          (row0 & (T_ - 1))) = pk;
            }
        }
}

// ===================== bf16 NT-GEMM: 256x128 tile, counted-vmcnt pipeline (R16-proven) ==
// Used for Wo (f32 out). A triple-buffered, B double-buffered; vmcnt(4) at K-tile entry.
__global__ __launch_bounds__(512) void gemm_bf16_256(
    const u16* __restrict__ A, const u16* __restrict__ W,
    float* __restrict__ Out, int M, int N, int K)
{
    __shared__ __align__(16) u16 AL[3][2][128 * 64];   // 96 KB
    __shared__ __align__(16) u16 BL[2][128 * 64];      // 32 KB
    const int tid = threadIdx.x;
    const int lane = tid & 63;
    const int w = tid >> 6;
    const int bm = blockIdx.y * 256;
    const int bn = blockIdx.x * 128;
    const int wm = (w >> 2) * 128;     // A half = w>>2
    const int wn = (w & 3) * 32;
    const int ah = w >> 2;
    const int lr = lane & 15, lg = lane >> 4;
    const int NKT = K >> 6;            // 16

    f32x4 acc[8][2];
    #pragma unroll
    for (int mi = 0; mi < 8; ++mi)
        #pragma unroll
        for (int ni = 0; ni < 2; ++ni) acc[mi][ni] = f32x4{0.f, 0.f, 0.f, 0.f};

    auto stageA = [&](int kt) {        // both halves, 4 loads FIFO
        const int db = kt % 3;
        #pragma unroll
        for (int hf = 0; hf < 2; ++hf)
            #pragma unroll
            for (int ci = 0; ci < 2; ++ci) {
                int c = tid + ci * 512;
                int l = c ^ (((c >> 5) & 1) << 1);
                gload_lds16(A + (size_t)(bm + hf * 128 + (l >> 3)) * K + kt * 64 + (l & 7) * 8,
                            (char*)&AL[db][hf][0] + c * 16);
            }
    };
    auto stageB = [&](int kt) {        // 2 loads
        const int db = kt & 1;
        #pragma unroll
        for (int ci = 0; ci < 2; ++ci) {
            int c = tid + ci * 512;
            int l = c ^ (((c >> 5) & 1) << 1);
            gload_lds16(W + (size_t)(bn + (l >> 3)) * K + kt * 64 + (l & 7) * 8,
                        (char*)&BL[db][0] + c * 16);
        }
    };

    stageA(0);
    stageB(0);
    stageA(1);                          // FIFO: [A0(4), B0(2), A1(4)]

    for (int kt = 0; kt < NKT; ++kt) {
        const int ab = kt % 3, bb = kt & 1;
        if (kt == NKT - 1) asm volatile("s_waitcnt vmcnt(0)" ::: "memory");
        else               asm volatile("s_waitcnt vmcnt(4)" ::: "memory");
        bar();                          // all waves' loads for K-tile kt landed
        #pragma unroll
        for (int ph = 0; ph < 2; ++ph) {
            bf16x8 af[4][2], bfm[2][2];
            #pragma unroll
            for (int mi2 = 0; mi2 < 4; ++mi2) {
                const int row = (ph * 4 + mi2) * 16 + lr;
                #pragma unroll
                for (int kk = 0; kk < 2; ++kk)
                    af[mi2][kk] = *(const bf16x8*)((const char*)&AL[ab][ah][0] +
                                                   swz(row * 128 + kk * 64 + lg * 16));
            }
            #pragma unroll
            for (int ni = 0; ni < 2; ++ni) {
                const int row = wn + ni * 16 + lr;
                #pragma unroll
                for (int kk = 0; kk < 2; ++kk)
                    bfm[ni][kk] = *(const bf16x8*)((const char*)&BL[bb][0] +
                                                   swz(row * 128 + kk * 64 + lg * 16));
            }
            if (ph == 0) { if (kt + 1 < NKT) stageB(kt + 1); }
            else         { if (kt + 2 < NKT) stageA(kt + 2); }
            bar();
            __builtin_amdgcn_s_setprio(1);
            #pragma unroll
            for (int mi2 = 0; mi2 < 4; ++mi2)
                #pragma unroll
                for (int ni = 0; ni < 2; ++ni)
                    #pragma unroll
                    for (int kk = 0; kk < 2; ++kk)
                        acc[ph * 4 + mi2][ni] = __builtin_amdgcn_mfma_f32_16x16x32_bf16(
                            af[mi2][kk], bfm[ni][kk], acc[ph * 4 + mi2][ni], 0, 0, 0);
            __builtin_amdgcn_s_setprio(0);
            bar();
        }
    }

    #pragma unroll
    for (int mi = 0; mi < 8; ++mi)
        #pragma unroll
        for (int ni = 0; ni < 2; ++ni) {
            const int row0 = bm + wm + mi * 16 + lg * 4;
            const int col = bn + wn + ni * 16 + lr;
            #pragma unroll
            for (int r = 0; r < 4; ++r)
                Out[(size_t)(row0 + r) * N + col] = acc[mi][ni][r];
        }
}

// ===================== Router + top-8 mask + gate + fused x->bf16 cast (R12-proven) ====
__global__ __launch_bounds__(64) void logits_mask_gate_kernel(
    const float* __restrict__ x, const float* __restrict__ Wr,
    const float* __restrict__ Wg, float* __restrict__ hm, float* __restrict__ gate,
    u16* __restrict__ xb)
{
    const int token = blockIdx.x;
    const int lane = threadIdx.x;
    const float* xr = x + (size_t)token * C_;
    __shared__ float lg[NH_];
    __shared__ float thr_s;
    float part[NH_];
    #pragma unroll
    for (int h = 0; h < NH_; ++h) part[h] = 0.f;
    for (int c = lane; c < C_; c += 64) {
        float xv = xr[c];
        xb[(size_t)token * C_ + c] = f2bf(xv);   // fused cast
        #pragma unroll
        for (int h = 0; h < NH_; ++h) part[h] = fmaf(xv, Wr[h * C_ + c], part[h]);
    }
    #pragma unroll
    for (int h = 0; h < NH_; ++h) {
        float s = part[h];
        #pragma unroll
        for (int off = 32; off; off >>= 1) s += __shfl_xor(s, off);
        if (lane == 0) lg[h] = s;
    }
    __syncthreads();
    if (lane == 0) {
        unsigned used = 0;
        float last = 0.f;
        for (int p = 0; p < KACT_; ++p) {
            float bv = -3.4e38f; int bi = 0;
            for (int i = 0; i < NH_; ++i)
                if (!(used & (1u << i)) && lg[i] > bv) { bv = lg[i]; bi = i; }
            used |= 1u << bi;
            last = bv;
        }
        thr_s = last;
    }
    __syncthreads();
    if (lane < NH_) hm[(size_t)token * NH_ + lane] = (lg[lane] >= thr_s) ? 1.f : 0.f;
    if (lane < NKV_) {
        float s = 0.f;
        #pragma unroll
        for (int g = 0; g < VG_; ++g) s = fmaf(xr[g], Wg[lane * VG_ + g], s);
        gate[(size_t)token * NKV_ + lane] = 2.f / (1.f + __expf(-s));
    }
}

// ===================== merged rotary + rms-norm (bf16 in, bf16 out, head-major) =======
// First 131072 vecs: q (heads=16, stride 1024, scale ql). Rest: k (heads=8, stride 512).
// Per-vec math identical to the R7-proven kernel; inputs now bf16 (QKV writes bf16).
__global__ __launch_bounds__(256) void rope_rms_kernel(
    const u16* __restrict__ qsrc, const u16* __restrict__ ksrc,
    u16* __restrict__ qdst, u16* __restrict__ kdst,
    const float* __restrict__ cosT, const float* __restrict__ sinT, float qscale)
{
    const int tid = threadIdx.x;
    const int gvec = blockIdx.x * 16 + (tid >> 4);
    const int idx = tid & 15;
    const u16* src; u16* dst; int vec, hshift, stride; float scale;
    if (gvec < 131072) { src = qsrc; dst = qdst; vec = gvec;          hshift = 4; stride = 1024; scale = qscale; }
    else               { src = ksrc; dst = kdst; vec = gvec - 131072; hshift = 3; stride = 512;  scale = 1.0f; }
    const int heads = 1 << hshift;
    const int m = vec >> hshift;
    const int hh = vec & (heads - 1);
    const int t = m & (T_ - 1);
    const int bb = m >> 11;
    const u16x4 uv = *(const u16x4*)(src + (size_t)m * stride + hh * 64 + idx * 4);
    const float4 c4 = *(const float4*)(cosT + t * 32 + (idx & 7) * 4);
    const float4 s4 = *(const float4*)(sinT + t * 32 + (idx & 7) * 4);
    float v0 = bf2f(uv[0]), v1 = bf2f(uv[1]), v2 = bf2f(uv[2]), v3 = bf2f(uv[3]);
    const float p0 = __shfl_xor(v0, 8);
    const float p1 = __shfl_xor(v1, 8);
    const float p2 = __shfl_xor(v2, 8);
    const float p3 = __shfl_xor(v3, 8);
    float r0, r1, r2, r3;
    if (idx < 8) {
        r0 = fmaf(v0, c4.x, p0 * s4.x); r1 = fmaf(v1, c4.y, p1 * s4.y);
        r2 = fmaf(v2, c4.z, p2 * s4.z); r3 = fmaf(v3, c4.w, p3 * s4.w);
    } else {
        r0 = fmaf(v0, c4.x, -p0 * s4.x); r1 = fmaf(v1, c4.y, -p1 * s4.y);
        r2 = fmaf(v2, c4.z, -p2 * s4.z); r3 = fmaf(v3, c4.w, -p3 * s4.w);
    }
    float ss = fmaf(r0, r0, fmaf(r1, r1, fmaf(r2, r2, r3 * r3)));
    ss += __shfl_xor(ss, 1);
    ss += __shfl_xor(ss, 2);
    ss += __shfl_xor(ss, 4);
    ss += __shfl_xor(ss, 8);
    const float sc = rsqrtf(ss * (1.0f / HD_) + EPS_) * scale;
    u16x4 o = { f2bf(r0 * sc), f2bf(r1 * sc), f2bf(r2 * sc), f2bf(r3 * sc) };
    *(u16x4*)(dst + ((size_t)(bb * heads + hh) * T_ + t) * HD_ + idx * 4) = o;
}

// ===================== MFMA flash attention v7 (R19-proven: balanced grid) ============
// bid = (15-qblk)*64 + b*16 + h; per-tile math R12-lineage (elementwise mask; branchy
// form BANNED: R9/R10). LDS staging REQUIRED (R13). Truncating P pack (R18-proven).
__global__ __launch_bounds__(512) void attn_mfma_kernel(
    const u16* __restrict__ qb, const u16* __restrict__ kb,
    const u16* __restrict__ vbT, const float* __restrict__ hm,
    u16* __restrict__ yb)
{
    __shared__ __align__(16) u16 Ks[64 * 72];
    __shared__ __align__(16) u16 Vt[64 * 72];
    __shared__ __align__(16) u16 Ps[8 * 16 * 72];
    const int bid = blockIdx.x;
    const int qblk = 15 - (bid >> 6);          // HIGH bits; reversed: longest first
    const int b = (bid >> 4) & 3;
    const int h = bid & 15;
    const int kv = h >> 1;
    const int tid = threadIdx.x;
    const int lane = tid & 63;
    const int w = tid >> 6;                    // 0..7
    const int lr = lane & 15;
    const int lg = lane >> 4;
    const int q0 = qblk * 128;
    const int qt_max = 2 * qblk + 1;

    bf16x8 qf[2];
    {
        const u16* src = qb + ((size_t)(b * NH_ + h) * T_ + q0 + w * 16 + lr) * HD_ + lg * 8;
        qf[0] = *(const bf16x8*)(src);
        qf[1] = *(const bf16x8*)(src + 32);
    }
    f32x4 yacc[4];
    #pragma unroll
    for (int dt = 0; dt < 4; ++dt) yacc[dt] = f32x4{0.f, 0.f, 0.f, 0.f};
    float m = -1e30f, l = 0.f;

    const u16* kbase = kb + (size_t)(b * NKV_ + kv) * T_ * HD_;            // head-major [t][64]
    const u16* vbase = vbT + ((size_t)(b * NKV_) + kv) * (size_t)HD_ * T_; // [d][t]
    u16* Pw = Ps + w * 16 * 72;
    const int qrow_g = q0 + w * 16 + lr;

    const int a0 = tid >> 3, g0 = tid & 7;
    bf16x8 kreg, vreg;
    auto LOADT = [&](int kt) {
        kreg = *(const bf16x8*)(kbase + (size_t)(kt * 64 + a0) * HD_ + g0 * 8);
        vreg = *(const bf16x8*)(vbase + (size_t)a0 * T_ + kt * 64 + g0 * 8);
    };
    auto WRITET = [&]() {
        *(bf16x8*)&Ks[a0 * 72 + g0 * 8] = kreg;
        *(bf16x8*)&Vt[a0 * 72 + g0 * 8] = vreg;
    };

    LOADT(0);
    WRITET();
    for (int kt = 0; kt <= qt_max; ++kt) {
        __syncthreads();                       // tile kt visible in LDS
        if (kt < qt_max) LOADT(kt + 1);        // prefetch next tile into regs
        const int rel = q0 + w * 16 + 15 - kt * 64;
        if (rel >= 0) {                        // wave-uniform skip of fully-masked tiles
            const int mtmax = min(3, rel >> 4);
            f32x4 st[4];
            #pragma unroll
            for (int mt = 0; mt < 4; ++mt) st[mt] = f32x4{0.f, 0.f, 0.f, 0.f};
            __builtin_amdgcn_s_setprio(1);
            #pragma unroll
            for (int mt = 0; mt < 4; ++mt) {
                if (mt <= mtmax) {
                    bf16x8 kf0 = *(const bf16x8*)&Ks[(mt * 16 + lr) * 72 + lg * 8];
                    bf16x8 kf1 = *(const bf16x8*)&Ks[(mt * 16 + lr) * 72 + lg * 8 + 32];
                    st[mt] = __builtin_amdgcn_mfma_f32_16x16x32_bf16(kf0, qf[0], st[mt], 0, 0, 0);
                    st[mt] = __builtin_amdgcn_mfma_f32_16x16x32_bf16(kf1, qf[1], st[mt], 0, 0, 0);
                }
            }
            __builtin_amdgcn_s_setprio(0);
            // mask + per-q max (elementwise PROVEN form)
            float smax = -1e30f;
            #pragma unroll
            for (int mt = 0; mt < 4; ++mt) {
                #pragma unroll
                for (int r = 0; r < 4; ++r) {
                    int keyg = kt * 64 + mt * 16 + lg * 4 + r;
                    float s = (mt <= mtmax && keyg <= qrow_g) ? st[mt][r] : -1e30f;
                    st[mt][r] = s;
                    smax = fmaxf(smax, s);
                }
            }
            smax = fmaxf(smax, __shfl_xor(smax, 16));
            smax = fmaxf(smax, __shfl_xor(smax, 32));
            if (!__all(smax <= m + 8.f)) {     // defer-max: P bounded by 2^8, bf16-safe
                const float mnew = fmaxf(m, smax);
                const float corr = fast_exp2(m - mnew);
                l *= corr;
                float cr[4];
                #pragma unroll
                for (int r = 0; r < 4; ++r) cr[r] = __shfl(corr, lg * 4 + r);
                #pragma unroll
                for (int dt = 0; dt < 4; ++dt)
                    #pragma unroll
                    for (int r = 0; r < 4; ++r) yacc[dt][r] *= cr[r];
                m = mnew;
            }
            float psum = 0.f;
            #pragma unroll
            for (int mt = 0; mt < 4; ++mt) {
                float p0 = fast_exp2(st[mt][0] - m);
                float p1 = fast_exp2(st[mt][1] - m);
                float p2 = fast_exp2(st[mt][2] - m);
                float p3 = fast_exp2(st[mt][3] - m);
                psum += (p0 + p1) + (p2 + p3);
                u16x4 pk = { f2bf_t(p0), f2bf_t(p1), f2bf_t(p2), f2bf_t(p3) };
                *(u16x4*)&Pw[lr * 72 + mt * 16 + lg * 4] = pk;
            }
            psum += __shfl_xor(psum, 16);
            psum += __shfl_xor(psum, 32);
            l += psum;
            // PV: Y[q][d] += P[q][s] * V[s][d]
            const int kimax = min(1, rel >> 5);
            __builtin_amdgcn_s_setprio(1);
            #pragma unroll
            for (int ki = 0; ki < 2; ++ki) {
                if (ki <= kimax) {
                    bf16x8 pf = *(const bf16x8*)&Pw[lr * 72 + ki * 32 + lg * 8];
                    #pragma unroll
                    for (int dt = 0; dt < 4; ++dt) {
                        bf16x8 vf = *(const bf16x8*)&Vt[(dt * 16 + lr) * 72 + ki * 32 + lg * 8];
                        yacc[dt] = __builtin_amdgcn_mfma_f32_16x16x32_bf16(pf, vf, yacc[dt], 0, 0, 0);
                    }
                }
            }
            __builtin_amdgcn_s_setprio(0);
        }
        __syncthreads();                       // all waves done reading tile kt
        if (kt < qt_max) WRITET();             // overwrite LDS with tile kt+1
    }
    const float linv = 1.f / l;
    #pragma unroll
    for (int r = 0; r < 4; ++r) {
        const float lrv = __shfl(linv, lg * 4 + r);
        const int t = q0 + w * 16 + lg * 4 + r;
        const float hmv = hm[((size_t)(b * T_) + t) * NH_ + h];
        const float sc = lrv * hmv;
        #pragma unroll
        for (int dt = 0; dt < 4; ++dt)
            yb[(((size_t)(b * T_) + t) * NH_ + h) * HD_ + dt * 16 + lr] = f2bf(yacc[dt][r] * sc);
    }
}

extern "C" void kernel_launch(void* const* d_in, const int* in_sizes, int n_in,
                              void* d_out, int out_size, void* d_ws, size_t ws_size,
                              hipStream_t stream) {
    const float* x    = (const float*)d_in[0];
    const float* ve   = (const float*)d_in[1];
    const float* cosT = (const float*)d_in[2];
    const float* sinT = (const float*)d_in[3];
    const float* Wq   = (const float*)d_in[4];
    const float* Wk   = (const float*)d_in[5];
    const float* Wv   = (const float*)d_in[6];
    const float* Wo   = (const float*)d_in[7];
    const float* Wr   = (const float*)d_in[8];
    const float* Wg   = (const float*)d_in[9];
    float* out = (float*)d_out;
    float* hm  = out + (size_t)B_ * T_ * C_;

    const int M = B_ * T_;  // 8192
    // Workspace (floats): total 16318464 f = 62.2 MiB (< proven 86.3 MiB extent)
    float* ws = (float*)d_ws;
    float* qtokr = ws;                  // 4194304 f (bf16 q token-major) [after rope: yb]
    float* ktokr = qtokr + 4194304;     // 2097152 f (bf16 k token-major)
    float* xbr   = ktokr + 2097152;     // 4194304 f (bf16 x) [after QKV: qb head-major]
    float* wqkvr = xbr + 4194304;       // 1048576 f (bf16 Wqkv)
    float* wor   = wqkvr + 1048576;     // 524288 f  (bf16 Wo)
    float* gate  = wor + 524288;        // 65536 f
    float* vtr   = gate + 65536;        // 2097152 f (bf16 vT [b][kv][d][t])
    float* kbr   = vtr + 2097152;       // 2097152 f (bf16 k roped, head-major)

    u16* qtok  = (u16*)qtokr;
    u16* ktok  = (u16*)ktokr;
    u16* xb    = (u16*)xbr;
    u16* Wqkvb = (u16*)wqkvr;
    u16* Wob   = (u16*)wor;
    u16* vbT   = (u16*)vtr;
    u16* qb    = (u16*)xbr;    // overlays xb (dead after QKV GEMM), head-major
    u16* kb    = (u16*)kbr;    // head-major
    u16* yb    = (u16*)qtokr;  // overlays qtok (dead after rope)

    // ---- weight casts ----
    cast_weights_kernel<<<3072, 256, 0, stream>>>(Wq, Wk, Wv, Wo, Wqkvb, Wob);
    // ---- router (gate feeds the fused V epilogue; also emits xb) ----
    logits_mask_gate_kernel<<<M, 64, 0, stream>>>(x, Wr, Wg, hm, gate, xb);
    // ---- fused QKV projection (BK=32, 64KB LDS, 2 blocks/CU; q,k bf16; v as vbT) ----
    gemm_qkv_bk32<<<dim3(2048 / 128, M / 256), 512, 0, stream>>>(
        xb, Wqkvb, M, C_, qtok, ktok, vbT, gate, ve);
    // ---- merged rope+rms (bf16 in) -> bf16 head-major ----
    rope_rms_kernel<<<(M * (NH_ + NKV_)) / 16, 256, 0, stream>>>(
        qtok, ktok, qb, kb, cosT, sinT, 0.125f * LOG2E_);
    // ---- flash attention (QBLK=128, 8 waves; balanced grid) ----
    attn_mfma_kernel<<<B_ * NH_ * (T_ / 128), 512, 0, stream>>>(qb, kb, vbT, hm, yb);
    // ---- output projection (R16 256x128 counted-vmcnt pipeline) ----
    gemm_bf16_256<<<dim3(C_ / 128, M / 256), 512, 0, stream>>>(
        yb, Wob, out, M, C_, C_);
}